// Round 1
// baseline (88189.716 us; speedup 1.0000x reference)
//
#include <hip/hip_runtime.h>
#include <stdint.h>
#include <math.h>

// Problem dims
#define Bn 256
#define Sn 512
#define En 256
#define Hn 256
#define Gn 1024            // 4*H
#define NSTEP 511          // S-1 decoder steps
#define MASK_VAL -100000.0

// JAX >= 0.5 defaults jax_threefry_partitionable=True. If indices come back
// wrong (uniform garbage), flip this to 0 to get the legacy bit derivation.
#define PARTITIONABLE 1

// ---------------------------------------------------------------- threefry
__device__ __forceinline__ uint32_t rotl32(uint32_t v, int d) {
  return (v << d) | (v >> (32 - d));
}

__device__ __forceinline__ void threefry2x32(uint32_t k0, uint32_t k1,
                                             uint32_t x0, uint32_t x1,
                                             uint32_t& o0, uint32_t& o1) {
  const uint32_t ks2 = k0 ^ k1 ^ 0x1BD11BDAu;
  x0 += k0; x1 += k1;
  x0 += x1; x1 = rotl32(x1, 13); x1 ^= x0;
  x0 += x1; x1 = rotl32(x1, 15); x1 ^= x0;
  x0 += x1; x1 = rotl32(x1, 26); x1 ^= x0;
  x0 += x1; x1 = rotl32(x1,  6); x1 ^= x0;
  x0 += k1; x1 += ks2 + 1u;
  x0 += x1; x1 = rotl32(x1, 17); x1 ^= x0;
  x0 += x1; x1 = rotl32(x1, 29); x1 ^= x0;
  x0 += x1; x1 = rotl32(x1, 16); x1 ^= x0;
  x0 += x1; x1 = rotl32(x1, 24); x1 ^= x0;
  x0 += ks2; x1 += k0 + 2u;
  x0 += x1; x1 = rotl32(x1, 13); x1 ^= x0;
  x0 += x1; x1 = rotl32(x1, 15); x1 ^= x0;
  x0 += x1; x1 = rotl32(x1, 26); x1 ^= x0;
  x0 += x1; x1 = rotl32(x1,  6); x1 ^= x0;
  x0 += k0; x1 += k1 + 3u;
  x0 += x1; x1 = rotl32(x1, 17); x1 ^= x0;
  x0 += x1; x1 = rotl32(x1, 29); x1 ^= x0;
  x0 += x1; x1 = rotl32(x1, 16); x1 ^= x0;
  x0 += x1; x1 = rotl32(x1, 24); x1 ^= x0;
  x0 += k1; x1 += ks2 + 4u;
  x0 += x1; x1 = rotl32(x1, 13); x1 ^= x0;
  x0 += x1; x1 = rotl32(x1, 15); x1 ^= x0;
  x0 += x1; x1 = rotl32(x1, 26); x1 ^= x0;
  x0 += x1; x1 = rotl32(x1,  6); x1 ^= x0;
  x0 += ks2; x1 += k0 + 5u;
  o0 = x0; o1 = x1;
}

// 32-bit random word for element n of a (B,S) draw with key (k0,k1),
// matching jax threefry random_bits.
__device__ __forceinline__ uint32_t random_word(uint32_t k0, uint32_t k1, uint32_t n) {
#if PARTITIONABLE
  uint32_t o0, o1;
  threefry2x32(k0, k1, 0u, n, o0, o1);      // counts1=hi(n)=0, counts2=lo(n)=n
  return o0 ^ o1;
#else
  const uint32_t half = (Bn * Sn) / 2;       // 65536
  uint32_t lane = (n < half) ? n : (n - half);
  uint32_t o0, o1;
  threefry2x32(k0, k1, lane, lane + half, o0, o1);
  return (n < half) ? o0 : o1;
#endif
}

__device__ __forceinline__ double sigmoid64(double x) {
  return 1.0 / (1.0 + exp(-x));
}

// ---------------------------------------------------------------- prep
// dst[c*rows + r] = (double)src[r*cols + c]
__global__ __launch_bounds__(256) void k_transpose64(const float* __restrict__ src,
                                                     double* __restrict__ dst,
                                                     int rows, int cols) {
  int idx = blockIdx.x * blockDim.x + threadIdx.x;
  if (idx >= rows * cols) return;
  int r = idx / cols, cc = idx % cols;
  dst[(size_t)cc * rows + r] = (double)src[idx];
}

// WihE[i][j] = sum_e W_embed[i][e] * Wih[j][e]   (i in {0,1}, j in [0,4H))
// bias[j] = bih[j] + bhh[j]
__global__ __launch_bounds__(256) void k_wihe(const float* __restrict__ wemb,
                                              const float* __restrict__ wih,
                                              const float* __restrict__ bih,
                                              const float* __restrict__ bhh,
                                              double* __restrict__ wihe,
                                              double* __restrict__ bias) {
  int j = blockIdx.x * blockDim.x + threadIdx.x;
  if (j >= Gn) return;
  double a0 = 0.0, a1 = 0.0;
  for (int e = 0; e < En; ++e) {
    double w = (double)wih[j * En + e];
    a0 += (double)wemb[e] * w;
    a1 += (double)wemb[En + e] * w;
  }
  wihe[j] = a0;
  wihe[Gn + j] = a1;
  bias[j] = (double)bih[j] + (double)bhh[j];
}

// keys for jax.random.split(key(1), 511); key(1) = (0,1)
__global__ __launch_bounds__(256) void k_keys(uint32_t* __restrict__ keys) {
  int j = blockIdx.x * blockDim.x + threadIdx.x;
  if (j >= NSTEP) return;
#if PARTITIONABLE
  uint32_t o0, o1;
  threefry2x32(0u, 1u, 0u, (uint32_t)j, o0, o1);
  keys[2 * j] = o0; keys[2 * j + 1] = o1;
#else
  uint32_t w[2];
  #pragma unroll
  for (int q = 0; q < 2; ++q) {
    uint32_t m = (uint32_t)(2 * j + q);
    uint32_t lane = (m < NSTEP) ? m : (m - NSTEP);
    uint32_t o0, o1;
    threefry2x32(0u, 1u, lane, lane + NSTEP, o0, o1);
    w[q] = (m < NSTEP) ? o0 : o1;
  }
  keys[2 * j] = w[0]; keys[2 * j + 1] = w[1];
#endif
}

__global__ __launch_bounds__(256) void k_init(double* __restrict__ h, double* __restrict__ c,
                                              int* __restrict__ mask, int* __restrict__ chosen,
                                              float* __restrict__ out) {
  int idx = blockIdx.x * blockDim.x + threadIdx.x;   // Bn*Sn threads
  if (idx < Bn * Hn) { h[idx] = 0.0; c[idx] = 0.0; }
  if (idx < Bn * Sn) mask[idx] = ((idx & (Sn - 1)) == 0) ? 1 : 0;  // mask[b][START=0]=1
  if (idx < Bn) {
    chosen[idx] = 0;                                  // START
    out[Bn * NSTEP + idx * Sn] = 0.0f;                // indices[:,0] = START
  }
}

// ---------------------------------------------------------------- encoder step
// One block = 2 batch rows. thread t owns gate rows {4t..4t+3}, then the cell
// update for hidden unit t, then ref_proj[b][s][t].
__global__ __launch_bounds__(256) void k_enc_step(
    const float* __restrict__ inp,      // (B,S,2)
    const double* __restrict__ wihe,    // (2,4H)
    const double* __restrict__ bias,    // (4H)
    const double* __restrict__ whhT,    // (H,4H)  whhT[k][j] = Whh[j][k]
    const double* __restrict__ wrefT,   // (H,H)   wrefT[k][t] = Wref[t][k]
    double* __restrict__ h,             // (B,H)
    double* __restrict__ c,             // (B,H)
    float* __restrict__ ref32,          // (B,S,H)
    int s) {
  __shared__ double sh_h[2][Hn];
  __shared__ double sh_g[2][Gn];
  const int tid = threadIdx.x;
  const int b0 = blockIdx.x * 2;

  sh_h[0][tid] = h[(size_t)b0 * Hn + tid];
  sh_h[1][tid] = h[(size_t)(b0 + 1) * Hn + tid];
  __syncthreads();

  double x00 = (double)inp[((size_t)b0 * Sn + s) * 2 + 0];
  double x01 = (double)inp[((size_t)b0 * Sn + s) * 2 + 1];
  double x10 = (double)inp[((size_t)(b0 + 1) * Sn + s) * 2 + 0];
  double x11 = (double)inp[((size_t)(b0 + 1) * Sn + s) * 2 + 1];

  double g0[4], g1[4];
  #pragma unroll
  for (int r = 0; r < 4; ++r) {
    int j = 4 * tid + r;
    double bb = bias[j];
    g0[r] = bb + x00 * wihe[j] + x01 * wihe[Gn + j];
    g1[r] = bb + x10 * wihe[j] + x11 * wihe[Gn + j];
  }
  for (int k = 0; k < Hn; ++k) {
    double h0k = sh_h[0][k], h1k = sh_h[1][k];
    const double* wrow = whhT + (size_t)k * Gn + 4 * tid;
    #pragma unroll
    for (int r = 0; r < 4; ++r) {
      double w = wrow[r];
      g0[r] += h0k * w;
      g1[r] += h1k * w;
    }
  }
  #pragma unroll
  for (int r = 0; r < 4; ++r) {
    sh_g[0][4 * tid + r] = g0[r];
    sh_g[1][4 * tid + r] = g1[r];
  }
  __syncthreads();

  #pragma unroll
  for (int bb = 0; bb < 2; ++bb) {
    double gi = sh_g[bb][tid];
    double gf = sh_g[bb][256 + tid];
    double gg = sh_g[bb][512 + tid];
    double go = sh_g[bb][768 + tid];
    size_t ix = (size_t)(b0 + bb) * Hn + tid;
    double cn = sigmoid64(gf) * c[ix] + sigmoid64(gi) * tanh(gg);
    double hn = sigmoid64(go) * tanh(cn);
    c[ix] = cn;
    h[ix] = hn;
    sh_h[bb][tid] = hn;
  }
  __syncthreads();

  double a0 = 0.0, a1 = 0.0;
  for (int k = 0; k < Hn; ++k) {
    double w = wrefT[(size_t)k * Hn + tid];
    a0 += sh_h[0][k] * w;
    a1 += sh_h[1][k] * w;
  }
  ref32[((size_t)b0 * Sn + s) * Hn + tid] = (float)a0;
  ref32[((size_t)(b0 + 1) * Sn + s) * Hn + tid] = (float)a1;
}

// ---------------------------------------------------------------- decoder cell
__global__ __launch_bounds__(256) void k_dec_cell(
    const float* __restrict__ inp,      // (B,S,2)
    const int* __restrict__ chosen,     // (B)
    const double* __restrict__ wihe,    // (2,4H)
    const double* __restrict__ bias,    // (4H)
    const double* __restrict__ whhT,    // (H,4H)
    const double* __restrict__ wqT,     // (H,H)
    double* __restrict__ h,
    double* __restrict__ c,
    float* __restrict__ q32) {          // (B,H)
  __shared__ double sh_h[2][Hn];
  __shared__ double sh_g[2][Gn];
  const int tid = threadIdx.x;
  const int b0 = blockIdx.x * 2;

  sh_h[0][tid] = h[(size_t)b0 * Hn + tid];
  sh_h[1][tid] = h[(size_t)(b0 + 1) * Hn + tid];
  __syncthreads();

  int cs0 = chosen[b0], cs1 = chosen[b0 + 1];
  double x00 = (double)inp[((size_t)b0 * Sn + cs0) * 2 + 0];
  double x01 = (double)inp[((size_t)b0 * Sn + cs0) * 2 + 1];
  double x10 = (double)inp[((size_t)(b0 + 1) * Sn + cs1) * 2 + 0];
  double x11 = (double)inp[((size_t)(b0 + 1) * Sn + cs1) * 2 + 1];

  double g0[4], g1[4];
  #pragma unroll
  for (int r = 0; r < 4; ++r) {
    int j = 4 * tid + r;
    double bb = bias[j];
    g0[r] = bb + x00 * wihe[j] + x01 * wihe[Gn + j];
    g1[r] = bb + x10 * wihe[j] + x11 * wihe[Gn + j];
  }
  for (int k = 0; k < Hn; ++k) {
    double h0k = sh_h[0][k], h1k = sh_h[1][k];
    const double* wrow = whhT + (size_t)k * Gn + 4 * tid;
    #pragma unroll
    for (int r = 0; r < 4; ++r) {
      double w = wrow[r];
      g0[r] += h0k * w;
      g1[r] += h1k * w;
    }
  }
  #pragma unroll
  for (int r = 0; r < 4; ++r) {
    sh_g[0][4 * tid + r] = g0[r];
    sh_g[1][4 * tid + r] = g1[r];
  }
  __syncthreads();

  #pragma unroll
  for (int bb = 0; bb < 2; ++bb) {
    double gi = sh_g[bb][tid];
    double gf = sh_g[bb][256 + tid];
    double gg = sh_g[bb][512 + tid];
    double go = sh_g[bb][768 + tid];
    size_t ix = (size_t)(b0 + bb) * Hn + tid;
    double cn = sigmoid64(gf) * c[ix] + sigmoid64(gi) * tanh(gg);
    double hn = sigmoid64(go) * tanh(cn);
    c[ix] = cn;
    h[ix] = hn;
    sh_h[bb][tid] = hn;
  }
  __syncthreads();

  double a0 = 0.0, a1 = 0.0;
  for (int k = 0; k < Hn; ++k) {
    double w = wqT[(size_t)k * Hn + tid];
    a0 += sh_h[0][k] * w;
    a1 += sh_h[1][k] * w;
  }
  q32[(size_t)b0 * Hn + tid] = (float)a0;
  q32[(size_t)(b0 + 1) * Hn + tid] = (float)a1;
}

// ---------------------------------------------------------------- attention + sample
// One block per batch row b. thread t owns s = t and s = t+256.
__global__ __launch_bounds__(256) void k_attn_sample(
    const float* __restrict__ q32,      // (B,H)
    const float* __restrict__ ref32,    // (B,S,H)
    const float* __restrict__ v,        // (H)
    int* __restrict__ mask,             // (B,S)
    const uint32_t* __restrict__ keys,  // (511,2)
    int* __restrict__ chosen,           // (B)
    float* __restrict__ out,            // d_out: [B*511 logprobs][B*512 indices]
    int t) {
  __shared__ float sq[Hn];
  __shared__ float sv[Hn];
  __shared__ double sl[Sn];
  __shared__ double redz[256];
  __shared__ double redm[256];
  __shared__ int redi[256];

  const int b = blockIdx.x;
  const int tid = threadIdx.x;
  sq[tid] = q32[(size_t)b * Hn + tid];
  sv[tid] = v[tid];
  __syncthreads();

  const uint32_t k0 = keys[2 * t], k1 = keys[2 * t + 1];

  double lv[2], zv[2];
  #pragma unroll
  for (int half = 0; half < 2; ++half) {
    int s = tid + half * 256;
    const float* rrow = ref32 + ((size_t)b * Sn + s) * Hn;
    double acc = 0.0;
    for (int hh = 0; hh < Hn; ++hh) {
      float arg = sq[hh] + rrow[hh];
      acc += (double)sv[hh] * (double)tanhf(arg);
    }
    double l = mask[(size_t)b * Sn + s] ? (double)MASK_VAL : acc;
    // gumbel noise, bit-exact uniform construction (f32 path), log in f64
    uint32_t n = (uint32_t)(b * Sn + s);
    uint32_t w = random_word(k0, k1, n);
    float uf = __uint_as_float((w >> 9) | 0x3f800000u) - 1.0f;
    uf = fmaxf(uf, 1.17549435e-38f);
    double g = -log(-log((double)uf));
    lv[half] = l;
    zv[half] = l + g;
    sl[s] = l;
  }

  // argmax over z, first-index tie-break (np.argmax semantics)
  double zb; int sb;
  if (zv[1] > zv[0]) { zb = zv[1]; sb = tid + 256; }
  else               { zb = zv[0]; sb = tid; }
  redz[tid] = zb; redi[tid] = sb;
  __syncthreads();
  for (int off = 128; off > 0; off >>= 1) {
    if (tid < off) {
      double zo = redz[tid + off]; int so = redi[tid + off];
      if (zo > redz[tid] || (zo == redz[tid] && so < redi[tid])) {
        redz[tid] = zo; redi[tid] = so;
      }
    }
    __syncthreads();
  }

  // log-softmax denominator over masked logits
  redm[tid] = fmax(lv[0], lv[1]);
  __syncthreads();
  for (int off = 128; off > 0; off >>= 1) {
    if (tid < off) redm[tid] = fmax(redm[tid], redm[tid + off]);
    __syncthreads();
  }
  double m = redm[0];
  __syncthreads();
  redm[tid] = exp(lv[0] - m) + exp(lv[1] - m);
  __syncthreads();
  for (int off = 128; off > 0; off >>= 1) {
    if (tid < off) redm[tid] += redm[tid + off];
    __syncthreads();
  }

  if (tid == 0) {
    int ch = redi[0];
    double lse = m + log(redm[0]);
    double lp = sl[ch] - lse;
    out[(size_t)b * NSTEP + t] = (float)lp;                 // logprobs[b][t]
    out[(size_t)Bn * NSTEP + (size_t)b * Sn + (t + 1)] = (float)ch;  // indices[b][t+1]
    mask[(size_t)b * Sn + ch] = 1;
    chosen[b] = ch;
  }
}

// ---------------------------------------------------------------- launch
extern "C" void kernel_launch(void* const* d_in, const int* in_sizes, int n_in,
                              void* d_out, int out_size, void* d_ws, size_t ws_size,
                              hipStream_t stream) {
  const float* inp  = (const float*)d_in[0];
  const float* wemb = (const float*)d_in[1];
  const float* eWih = (const float*)d_in[2];
  const float* eWhh = (const float*)d_in[3];
  const float* ebih = (const float*)d_in[4];
  const float* ebhh = (const float*)d_in[5];
  const float* dWih = (const float*)d_in[6];
  const float* dWhh = (const float*)d_in[7];
  const float* dbih = (const float*)d_in[8];
  const float* dbhh = (const float*)d_in[9];
  const float* Wq   = (const float*)d_in[10];
  const float* Wref = (const float*)d_in[11];
  const float* v    = (const float*)d_in[12];
  float* out = (float*)d_out;

  char* ws = (char*)d_ws;
  size_t off = 0;
  auto alloc = [&](size_t bytes) -> void* {
    void* p = (void*)(ws + off);
    off += (bytes + 255) & ~(size_t)255;
    return p;
  };
  float*    ref32  = (float*)   alloc((size_t)Bn * Sn * Hn * sizeof(float));   // 134 MB
  double*   whhT_e = (double*)  alloc((size_t)Gn * Hn * sizeof(double));
  double*   whhT_d = (double*)  alloc((size_t)Gn * Hn * sizeof(double));
  double*   wqT    = (double*)  alloc((size_t)Hn * Hn * sizeof(double));
  double*   wrefT  = (double*)  alloc((size_t)Hn * Hn * sizeof(double));
  double*   wihe_e = (double*)  alloc(2 * Gn * sizeof(double));
  double*   wihe_d = (double*)  alloc(2 * Gn * sizeof(double));
  double*   bias_e = (double*)  alloc(Gn * sizeof(double));
  double*   bias_d = (double*)  alloc(Gn * sizeof(double));
  double*   h      = (double*)  alloc((size_t)Bn * Hn * sizeof(double));
  double*   c      = (double*)  alloc((size_t)Bn * Hn * sizeof(double));
  float*    q32    = (float*)   alloc((size_t)Bn * Hn * sizeof(float));
  int*      maskp  = (int*)     alloc((size_t)Bn * Sn * sizeof(int));
  int*      chosen = (int*)     alloc(Bn * sizeof(int));
  uint32_t* keys   = (uint32_t*)alloc(2 * NSTEP * sizeof(uint32_t));
  (void)ws_size; (void)in_sizes; (void)n_in; (void)out_size;

  k_transpose64<<<(Gn * Hn) / 256, 256, 0, stream>>>(eWhh, whhT_e, Gn, Hn);
  k_transpose64<<<(Gn * Hn) / 256, 256, 0, stream>>>(dWhh, whhT_d, Gn, Hn);
  k_transpose64<<<(Hn * Hn) / 256, 256, 0, stream>>>(Wq, wqT, Hn, Hn);
  k_transpose64<<<(Hn * Hn) / 256, 256, 0, stream>>>(Wref, wrefT, Hn, Hn);
  k_wihe<<<Gn / 256, 256, 0, stream>>>(wemb, eWih, ebih, ebhh, wihe_e, bias_e);
  k_wihe<<<Gn / 256, 256, 0, stream>>>(wemb, dWih, dbih, dbhh, wihe_d, bias_d);
  k_keys<<<2, 256, 0, stream>>>(keys);
  k_init<<<(Bn * Sn) / 256, 256, 0, stream>>>(h, c, maskp, chosen, out);

  for (int s = 0; s < Sn; ++s)
    k_enc_step<<<Bn / 2, 256, 0, stream>>>(inp, wihe_e, bias_e, whhT_e, wrefT, h, c, ref32, s);

  for (int t = 0; t < NSTEP; ++t) {
    k_dec_cell<<<Bn / 2, 256, 0, stream>>>(inp, chosen, wihe_d, bias_d, whhT_d, wqT, h, c, q32);
    k_attn_sample<<<Bn, 256, 0, stream>>>(q32, ref32, v, maskp, keys, chosen, out, t);
  }
}

// Round 2
// 55917.218 us; speedup vs baseline: 1.5771x; 1.5771x over previous
//
#include <hip/hip_runtime.h>
#include <stdint.h>
#include <math.h>

// Problem dims
#define Bn 256
#define Sn 512
#define En 256
#define Hn 256
#define Gn 1024            // 4*H
#define NSTEP 511          // S-1 decoder steps
#define MASK_VAL -100000.0

// Verified round 1: partitionable threefry + f64 compute path gives absmax=0.
#define PARTITIONABLE 1

// ---------------------------------------------------------------- threefry
__device__ __forceinline__ uint32_t rotl32(uint32_t v, int d) {
  return (v << d) | (v >> (32 - d));
}

__device__ __forceinline__ void threefry2x32(uint32_t k0, uint32_t k1,
                                             uint32_t x0, uint32_t x1,
                                             uint32_t& o0, uint32_t& o1) {
  const uint32_t ks2 = k0 ^ k1 ^ 0x1BD11BDAu;
  x0 += k0; x1 += k1;
  x0 += x1; x1 = rotl32(x1, 13); x1 ^= x0;
  x0 += x1; x1 = rotl32(x1, 15); x1 ^= x0;
  x0 += x1; x1 = rotl32(x1, 26); x1 ^= x0;
  x0 += x1; x1 = rotl32(x1,  6); x1 ^= x0;
  x0 += k1; x1 += ks2 + 1u;
  x0 += x1; x1 = rotl32(x1, 17); x1 ^= x0;
  x0 += x1; x1 = rotl32(x1, 29); x1 ^= x0;
  x0 += x1; x1 = rotl32(x1, 16); x1 ^= x0;
  x0 += x1; x1 = rotl32(x1, 24); x1 ^= x0;
  x0 += ks2; x1 += k0 + 2u;
  x0 += x1; x1 = rotl32(x1, 13); x1 ^= x0;
  x0 += x1; x1 = rotl32(x1, 15); x1 ^= x0;
  x0 += x1; x1 = rotl32(x1, 26); x1 ^= x0;
  x0 += x1; x1 = rotl32(x1,  6); x1 ^= x0;
  x0 += k0; x1 += k1 + 3u;
  x0 += x1; x1 = rotl32(x1, 17); x1 ^= x0;
  x0 += x1; x1 = rotl32(x1, 29); x1 ^= x0;
  x0 += x1; x1 = rotl32(x1, 16); x1 ^= x0;
  x0 += x1; x1 = rotl32(x1, 24); x1 ^= x0;
  x0 += k1; x1 += ks2 + 4u;
  x0 += x1; x1 = rotl32(x1, 13); x1 ^= x0;
  x0 += x1; x1 = rotl32(x1, 15); x1 ^= x0;
  x0 += x1; x1 = rotl32(x1, 26); x1 ^= x0;
  x0 += x1; x1 = rotl32(x1,  6); x1 ^= x0;
  x0 += ks2; x1 += k0 + 5u;
  o0 = x0; o1 = x1;
}

__device__ __forceinline__ uint32_t random_word(uint32_t k0, uint32_t k1, uint32_t n) {
#if PARTITIONABLE
  uint32_t o0, o1;
  threefry2x32(k0, k1, 0u, n, o0, o1);
  return o0 ^ o1;
#else
  const uint32_t half = (Bn * Sn) / 2;
  uint32_t lane = (n < half) ? n : (n - half);
  uint32_t o0, o1;
  threefry2x32(k0, k1, lane, lane + half, o0, o1);
  return (n < half) ? o0 : o1;
#endif
}

__device__ __forceinline__ double sigmoid64(double x) {
  return 1.0 / (1.0 + exp(-x));
}

// ---------------------------------------------------------------- prep
__global__ __launch_bounds__(256) void k_transpose64(const float* __restrict__ src,
                                                     double* __restrict__ dst,
                                                     int rows, int cols) {
  int idx = blockIdx.x * blockDim.x + threadIdx.x;
  if (idx >= rows * cols) return;
  int r = idx / cols, cc = idx % cols;
  dst[(size_t)cc * rows + r] = (double)src[idx];
}

__global__ __launch_bounds__(256) void k_wihe(const float* __restrict__ wemb,
                                              const float* __restrict__ wih,
                                              const float* __restrict__ bih,
                                              const float* __restrict__ bhh,
                                              double* __restrict__ wihe,
                                              double* __restrict__ bias) {
  int j = blockIdx.x * blockDim.x + threadIdx.x;
  if (j >= Gn) return;
  double a0 = 0.0, a1 = 0.0;
  for (int e = 0; e < En; ++e) {
    double w = (double)wih[j * En + e];
    a0 += (double)wemb[e] * w;
    a1 += (double)wemb[En + e] * w;
  }
  wihe[j] = a0;
  wihe[Gn + j] = a1;
  bias[j] = (double)bih[j] + (double)bhh[j];
}

__global__ __launch_bounds__(256) void k_keys(uint32_t* __restrict__ keys) {
  int j = blockIdx.x * blockDim.x + threadIdx.x;
  if (j >= NSTEP) return;
#if PARTITIONABLE
  uint32_t o0, o1;
  threefry2x32(0u, 1u, 0u, (uint32_t)j, o0, o1);
  keys[2 * j] = o0; keys[2 * j + 1] = o1;
#else
  uint32_t w[2];
  #pragma unroll
  for (int q = 0; q < 2; ++q) {
    uint32_t m = (uint32_t)(2 * j + q);
    uint32_t lane = (m < NSTEP) ? m : (m - NSTEP);
    uint32_t o0, o1;
    threefry2x32(0u, 1u, lane, lane + NSTEP, o0, o1);
    w[q] = (m < NSTEP) ? o0 : o1;
  }
  keys[2 * j] = w[0]; keys[2 * j + 1] = w[1];
#endif
}

__global__ __launch_bounds__(256) void k_init(double* __restrict__ h, double* __restrict__ c,
                                              int* __restrict__ mask, int* __restrict__ chosen,
                                              float* __restrict__ out) {
  int idx = blockIdx.x * blockDim.x + threadIdx.x;
  if (idx < Bn * Hn) { h[idx] = 0.0; c[idx] = 0.0; }
  if (idx < Bn * Sn) mask[idx] = ((idx & (Sn - 1)) == 0) ? 1 : 0;
  if (idx < Bn) {
    chosen[idx] = 0;
    out[Bn * NSTEP + idx * Sn] = 0.0f;
  }
}

// ---------------------------------------------------------------- encoder step
__global__ __launch_bounds__(256) void k_enc_step(
    const float* __restrict__ inp,
    const double* __restrict__ wihe,
    const double* __restrict__ bias,
    const double* __restrict__ whhT,
    const double* __restrict__ wrefT,
    double* __restrict__ h,
    double* __restrict__ c,
    float* __restrict__ ref32,
    int s) {
  __shared__ double sh_h[2][Hn];
  __shared__ double sh_g[2][Gn];
  const int tid = threadIdx.x;
  const int b0 = blockIdx.x * 2;

  sh_h[0][tid] = h[(size_t)b0 * Hn + tid];
  sh_h[1][tid] = h[(size_t)(b0 + 1) * Hn + tid];
  __syncthreads();

  double x00 = (double)inp[((size_t)b0 * Sn + s) * 2 + 0];
  double x01 = (double)inp[((size_t)b0 * Sn + s) * 2 + 1];
  double x10 = (double)inp[((size_t)(b0 + 1) * Sn + s) * 2 + 0];
  double x11 = (double)inp[((size_t)(b0 + 1) * Sn + s) * 2 + 1];

  double g0[4], g1[4];
  #pragma unroll
  for (int r = 0; r < 4; ++r) {
    int j = 4 * tid + r;
    double bb = bias[j];
    g0[r] = bb + x00 * wihe[j] + x01 * wihe[Gn + j];
    g1[r] = bb + x10 * wihe[j] + x11 * wihe[Gn + j];
  }
  for (int k = 0; k < Hn; ++k) {
    double h0k = sh_h[0][k], h1k = sh_h[1][k];
    const double* wrow = whhT + (size_t)k * Gn + 4 * tid;
    #pragma unroll
    for (int r = 0; r < 4; ++r) {
      double w = wrow[r];
      g0[r] += h0k * w;
      g1[r] += h1k * w;
    }
  }
  #pragma unroll
  for (int r = 0; r < 4; ++r) {
    sh_g[0][4 * tid + r] = g0[r];
    sh_g[1][4 * tid + r] = g1[r];
  }
  __syncthreads();

  #pragma unroll
  for (int bb = 0; bb < 2; ++bb) {
    double gi = sh_g[bb][tid];
    double gf = sh_g[bb][256 + tid];
    double gg = sh_g[bb][512 + tid];
    double go = sh_g[bb][768 + tid];
    size_t ix = (size_t)(b0 + bb) * Hn + tid;
    double cn = sigmoid64(gf) * c[ix] + sigmoid64(gi) * tanh(gg);
    double hn = sigmoid64(go) * tanh(cn);
    c[ix] = cn;
    h[ix] = hn;
    sh_h[bb][tid] = hn;
  }
  __syncthreads();

  double a0 = 0.0, a1 = 0.0;
  for (int k = 0; k < Hn; ++k) {
    double w = wrefT[(size_t)k * Hn + tid];
    a0 += sh_h[0][k] * w;
    a1 += sh_h[1][k] * w;
  }
  ref32[((size_t)b0 * Sn + s) * Hn + tid] = (float)a0;
  ref32[((size_t)(b0 + 1) * Sn + s) * Hn + tid] = (float)a1;
}

// ---------------------------------------------------------------- decoder cell
__global__ __launch_bounds__(256) void k_dec_cell(
    const float* __restrict__ inp,
    const int* __restrict__ chosen,
    const double* __restrict__ wihe,
    const double* __restrict__ bias,
    const double* __restrict__ whhT,
    const double* __restrict__ wqT,
    double* __restrict__ h,
    double* __restrict__ c,
    float* __restrict__ q32) {
  __shared__ double sh_h[2][Hn];
  __shared__ double sh_g[2][Gn];
  const int tid = threadIdx.x;
  const int b0 = blockIdx.x * 2;

  sh_h[0][tid] = h[(size_t)b0 * Hn + tid];
  sh_h[1][tid] = h[(size_t)(b0 + 1) * Hn + tid];
  __syncthreads();

  int cs0 = chosen[b0], cs1 = chosen[b0 + 1];
  double x00 = (double)inp[((size_t)b0 * Sn + cs0) * 2 + 0];
  double x01 = (double)inp[((size_t)b0 * Sn + cs0) * 2 + 1];
  double x10 = (double)inp[((size_t)(b0 + 1) * Sn + cs1) * 2 + 0];
  double x11 = (double)inp[((size_t)(b0 + 1) * Sn + cs1) * 2 + 1];

  double g0[4], g1[4];
  #pragma unroll
  for (int r = 0; r < 4; ++r) {
    int j = 4 * tid + r;
    double bb = bias[j];
    g0[r] = bb + x00 * wihe[j] + x01 * wihe[Gn + j];
    g1[r] = bb + x10 * wihe[j] + x11 * wihe[Gn + j];
  }
  for (int k = 0; k < Hn; ++k) {
    double h0k = sh_h[0][k], h1k = sh_h[1][k];
    const double* wrow = whhT + (size_t)k * Gn + 4 * tid;
    #pragma unroll
    for (int r = 0; r < 4; ++r) {
      double w = wrow[r];
      g0[r] += h0k * w;
      g1[r] += h1k * w;
    }
  }
  #pragma unroll
  for (int r = 0; r < 4; ++r) {
    sh_g[0][4 * tid + r] = g0[r];
    sh_g[1][4 * tid + r] = g1[r];
  }
  __syncthreads();

  #pragma unroll
  for (int bb = 0; bb < 2; ++bb) {
    double gi = sh_g[bb][tid];
    double gf = sh_g[bb][256 + tid];
    double gg = sh_g[bb][512 + tid];
    double go = sh_g[bb][768 + tid];
    size_t ix = (size_t)(b0 + bb) * Hn + tid;
    double cn = sigmoid64(gf) * c[ix] + sigmoid64(gi) * tanh(gg);
    double hn = sigmoid64(go) * tanh(cn);
    c[ix] = cn;
    h[ix] = hn;
    sh_h[bb][tid] = hn;
  }
  __syncthreads();

  double a0 = 0.0, a1 = 0.0;
  for (int k = 0; k < Hn; ++k) {
    double w = wqT[(size_t)k * Hn + tid];
    a0 += sh_h[0][k] * w;
    a1 += sh_h[1][k] * w;
  }
  q32[(size_t)b0 * Hn + tid] = (float)a0;
  q32[(size_t)(b0 + 1) * Hn + tid] = (float)a1;
}

// ---------------------------------------------------------------- attention + sample
// 1024 threads (16 waves) per block, one block per batch row.
// Phase 1: wave w owns s = w*32..w*32+31; lane l float4-loads ref[s][4l..4l+3]
//          (wave reads 1 KB contiguous), 4 tanh terms with ILP-4, f64 butterfly
//          reduce -> logit sl[s].
// Phase 2: threads 0..511 in parallel: mask, threefry, gumbel -> z[s].
// Phase 3: wave0 argmax(z) | wave1 max+logsumexp(sl)  (concurrent waves).
__global__ __launch_bounds__(1024) void k_attn_sample(
    const float* __restrict__ q32,      // (B,H)
    const float* __restrict__ ref32,    // (B,S,H)
    const float* __restrict__ v,        // (H)
    int* __restrict__ mask,             // (B,S)
    const uint32_t* __restrict__ keys,  // (511,2)
    int* __restrict__ chosen,           // (B)
    float* __restrict__ out,            // [B*511 logprobs][B*512 indices]
    int t) {
  __shared__ float4 sq4[64];
  __shared__ float4 sv4[64];
  __shared__ double sl[Sn];     // masked logits (f64)
  __shared__ double zz[Sn];     // gumbel-perturbed
  __shared__ int    sch;
  __shared__ double smax, slse;

  const int b   = blockIdx.x;
  const int tid = threadIdx.x;
  const int w   = tid >> 6;
  const int l   = tid & 63;

  if (tid < 64)        sq4[tid]      = ((const float4*)(q32 + (size_t)b * Hn))[tid];
  else if (tid < 128)  sv4[tid - 64] = ((const float4*)v)[tid - 64];
  __syncthreads();

  // ---- phase 1: logits
  {
    const float4 qv = sq4[l];
    const float4 vv = sv4[l];
    const float4* rbase = (const float4*)(ref32 + ((size_t)b * Sn) * Hn);
    #pragma unroll 2
    for (int p = 0; p < 32; ++p) {
      const int s = w * 32 + p;
      float4 rr = rbase[(size_t)s * 64 + l];
      double acc = (double)vv.x * (double)tanhf(qv.x + rr.x)
                 + (double)vv.y * (double)tanhf(qv.y + rr.y)
                 + (double)vv.z * (double)tanhf(qv.z + rr.z)
                 + (double)vv.w * (double)tanhf(qv.w + rr.w);
      #pragma unroll
      for (int m = 32; m >= 1; m >>= 1) acc += __shfl_xor(acc, m);
      if (l == 0) sl[s] = acc;
    }
  }
  __syncthreads();

  // ---- phase 2: mask + gumbel (threads 0..511)
  const uint32_t k0 = keys[2 * t], k1 = keys[2 * t + 1];
  if (tid < Sn) {
    const int s = tid;
    double lg = mask[(size_t)b * Sn + s] ? (double)MASK_VAL : sl[s];
    uint32_t n = (uint32_t)(b * Sn + s);
    uint32_t wrd = random_word(k0, k1, n);
    float uf = __uint_as_float((wrd >> 9) | 0x3f800000u) - 1.0f;
    uf = fmaxf(uf, 1.17549435e-38f);
    double g = -log(-log((double)uf));
    sl[s] = lg;
    zz[s] = lg + g;
  }
  __syncthreads();

  // ---- phase 3a (wave 0): argmax over zz, first-index tie-break
  if (w == 0) {
    double bz = zz[l]; int bi = l;
    #pragma unroll
    for (int k = 1; k < 8; ++k) {
      int s2 = l + k * 64;
      double z2 = zz[s2];
      if (z2 > bz || (z2 == bz && s2 < bi)) { bz = z2; bi = s2; }
    }
    #pragma unroll
    for (int m = 32; m >= 1; m >>= 1) {
      double oz = __shfl_xor(bz, m);
      int    oi = __shfl_xor(bi, m);
      if (oz > bz || (oz == bz && oi < bi)) { bz = oz; bi = oi; }
    }
    if (l == 0) sch = bi;
  }
  // ---- phase 3b (wave 1): max + logsumexp over sl
  if (w == 1) {
    double bm = sl[l];
    #pragma unroll
    for (int k = 1; k < 8; ++k) bm = fmax(bm, sl[l + k * 64]);
    #pragma unroll
    for (int m = 32; m >= 1; m >>= 1) bm = fmax(bm, __shfl_xor(bm, m));
    double ps = 0.0;
    #pragma unroll
    for (int k = 0; k < 8; ++k) ps += exp(sl[l + k * 64] - bm);
    #pragma unroll
    for (int m = 32; m >= 1; m >>= 1) ps += __shfl_xor(ps, m);
    if (l == 0) { smax = bm; slse = bm + log(ps); }
  }
  __syncthreads();

  if (tid == 0) {
    int ch = sch;
    double lp = sl[ch] - slse;
    out[(size_t)b * NSTEP + t] = (float)lp;
    out[(size_t)Bn * NSTEP + (size_t)b * Sn + (t + 1)] = (float)ch;
    mask[(size_t)b * Sn + ch] = 1;
    chosen[b] = ch;
  }
}

// ---------------------------------------------------------------- launch
extern "C" void kernel_launch(void* const* d_in, const int* in_sizes, int n_in,
                              void* d_out, int out_size, void* d_ws, size_t ws_size,
                              hipStream_t stream) {
  const float* inp  = (const float*)d_in[0];
  const float* wemb = (const float*)d_in[1];
  const float* eWih = (const float*)d_in[2];
  const float* eWhh = (const float*)d_in[3];
  const float* ebih = (const float*)d_in[4];
  const float* ebhh = (const float*)d_in[5];
  const float* dWih = (const float*)d_in[6];
  const float* dWhh = (const float*)d_in[7];
  const float* dbih = (const float*)d_in[8];
  const float* dbhh = (const float*)d_in[9];
  const float* Wq   = (const float*)d_in[10];
  const float* Wref = (const float*)d_in[11];
  const float* v    = (const float*)d_in[12];
  float* out = (float*)d_out;

  char* ws = (char*)d_ws;
  size_t off = 0;
  auto alloc = [&](size_t bytes) -> void* {
    void* p = (void*)(ws + off);
    off += (bytes + 255) & ~(size_t)255;
    return p;
  };
  float*    ref32  = (float*)   alloc((size_t)Bn * Sn * Hn * sizeof(float));
  double*   whhT_e = (double*)  alloc((size_t)Gn * Hn * sizeof(double));
  double*   whhT_d = (double*)  alloc((size_t)Gn * Hn * sizeof(double));
  double*   wqT    = (double*)  alloc((size_t)Hn * Hn * sizeof(double));
  double*   wrefT  = (double*)  alloc((size_t)Hn * Hn * sizeof(double));
  double*   wihe_e = (double*)  alloc(2 * Gn * sizeof(double));
  double*   wihe_d = (double*)  alloc(2 * Gn * sizeof(double));
  double*   bias_e = (double*)  alloc(Gn * sizeof(double));
  double*   bias_d = (double*)  alloc(Gn * sizeof(double));
  double*   h      = (double*)  alloc((size_t)Bn * Hn * sizeof(double));
  double*   c      = (double*)  alloc((size_t)Bn * Hn * sizeof(double));
  float*    q32    = (float*)   alloc((size_t)Bn * Hn * sizeof(float));
  int*      maskp  = (int*)     alloc((size_t)Bn * Sn * sizeof(int));
  int*      chosen = (int*)     alloc(Bn * sizeof(int));
  uint32_t* keys   = (uint32_t*)alloc(2 * NSTEP * sizeof(uint32_t));
  (void)ws_size; (void)in_sizes; (void)n_in; (void)out_size;

  k_transpose64<<<(Gn * Hn) / 256, 256, 0, stream>>>(eWhh, whhT_e, Gn, Hn);
  k_transpose64<<<(Gn * Hn) / 256, 256, 0, stream>>>(dWhh, whhT_d, Gn, Hn);
  k_transpose64<<<(Hn * Hn) / 256, 256, 0, stream>>>(Wq, wqT, Hn, Hn);
  k_transpose64<<<(Hn * Hn) / 256, 256, 0, stream>>>(Wref, wrefT, Hn, Hn);
  k_wihe<<<Gn / 256, 256, 0, stream>>>(wemb, eWih, ebih, ebhh, wihe_e, bias_e);
  k_wihe<<<Gn / 256, 256, 0, stream>>>(wemb, dWih, dbih, dbhh, wihe_d, bias_d);
  k_keys<<<2, 256, 0, stream>>>(keys);
  k_init<<<(Bn * Sn) / 256, 256, 0, stream>>>(h, c, maskp, chosen, out);

  for (int s = 0; s < Sn; ++s)
    k_enc_step<<<Bn / 2, 256, 0, stream>>>(inp, wihe_e, bias_e, whhT_e, wrefT, h, c, ref32, s);

  for (int t = 0; t < NSTEP; ++t) {
    k_dec_cell<<<Bn / 2, 256, 0, stream>>>(inp, chosen, wihe_d, bias_d, whhT_d, wqT, h, c, q32);
    k_attn_sample<<<Bn, 1024, 0, stream>>>(q32, ref32, v, maskp, keys, chosen, out, t);
  }
}

// Round 3
// 42205.191 us; speedup vs baseline: 2.0895x; 1.3249x over previous
//
#include <hip/hip_runtime.h>
#include <stdint.h>
#include <math.h>

// Problem dims
#define Bn 256
#define Sn 512
#define En 256
#define Hn 256
#define Gn 1024            // 4*H
#define NSTEP 511          // S-1 decoder steps
#define MASK_VAL -100000.0

// Verified round 1/2: partitionable threefry + f64 compute path → absmax=0.
#define PARTITIONABLE 1

// ---------------------------------------------------------------- threefry
__device__ __forceinline__ uint32_t rotl32(uint32_t v, int d) {
  return (v << d) | (v >> (32 - d));
}

__device__ __forceinline__ void threefry2x32(uint32_t k0, uint32_t k1,
                                             uint32_t x0, uint32_t x1,
                                             uint32_t& o0, uint32_t& o1) {
  const uint32_t ks2 = k0 ^ k1 ^ 0x1BD11BDAu;
  x0 += k0; x1 += k1;
  x0 += x1; x1 = rotl32(x1, 13); x1 ^= x0;
  x0 += x1; x1 = rotl32(x1, 15); x1 ^= x0;
  x0 += x1; x1 = rotl32(x1, 26); x1 ^= x0;
  x0 += x1; x1 = rotl32(x1,  6); x1 ^= x0;
  x0 += k1; x1 += ks2 + 1u;
  x0 += x1; x1 = rotl32(x1, 17); x1 ^= x0;
  x0 += x1; x1 = rotl32(x1, 29); x1 ^= x0;
  x0 += x1; x1 = rotl32(x1, 16); x1 ^= x0;
  x0 += x1; x1 = rotl32(x1, 24); x1 ^= x0;
  x0 += ks2; x1 += k0 + 2u;
  x0 += x1; x1 = rotl32(x1, 13); x1 ^= x0;
  x0 += x1; x1 = rotl32(x1, 15); x1 ^= x0;
  x0 += x1; x1 = rotl32(x1, 26); x1 ^= x0;
  x0 += x1; x1 = rotl32(x1,  6); x1 ^= x0;
  x0 += k0; x1 += k1 + 3u;
  x0 += x1; x1 = rotl32(x1, 17); x1 ^= x0;
  x0 += x1; x1 = rotl32(x1, 29); x1 ^= x0;
  x0 += x1; x1 = rotl32(x1, 16); x1 ^= x0;
  x0 += x1; x1 = rotl32(x1, 24); x1 ^= x0;
  x0 += k1; x1 += ks2 + 4u;
  x0 += x1; x1 = rotl32(x1, 13); x1 ^= x0;
  x0 += x1; x1 = rotl32(x1, 15); x1 ^= x0;
  x0 += x1; x1 = rotl32(x1, 26); x1 ^= x0;
  x0 += x1; x1 = rotl32(x1,  6); x1 ^= x0;
  x0 += ks2; x1 += k0 + 5u;
  o0 = x0; o1 = x1;
}

__device__ __forceinline__ uint32_t random_word(uint32_t k0, uint32_t k1, uint32_t n) {
#if PARTITIONABLE
  uint32_t o0, o1;
  threefry2x32(k0, k1, 0u, n, o0, o1);
  return o0 ^ o1;
#else
  const uint32_t half = (Bn * Sn) / 2;
  uint32_t lane = (n < half) ? n : (n - half);
  uint32_t o0, o1;
  threefry2x32(k0, k1, lane, lane + half, o0, o1);
  return (n < half) ? o0 : o1;
#endif
}

__device__ __forceinline__ double sigmoid64(double x) {
  return 1.0 / (1.0 + exp(-x));
}

// ---------------------------------------------------------------- prep
// WihE[i][j] = sum_e W_embed[i][e]*Wih[j][e] (f64);  bias[j] = bih[j]+bhh[j]
__global__ __launch_bounds__(256) void k_wihe(const float* __restrict__ wemb,
                                              const float* __restrict__ wih,
                                              const float* __restrict__ bih,
                                              const float* __restrict__ bhh,
                                              double* __restrict__ wihe,
                                              double* __restrict__ bias) {
  int j = blockIdx.x * blockDim.x + threadIdx.x;
  if (j >= Gn) return;
  double a0 = 0.0, a1 = 0.0;
  for (int e = 0; e < En; ++e) {
    double w = (double)wih[j * En + e];
    a0 += (double)wemb[e] * w;
    a1 += (double)wemb[En + e] * w;
  }
  wihe[j] = a0;
  wihe[Gn + j] = a1;
  bias[j] = (double)bih[j] + (double)bhh[j];
}

__global__ __launch_bounds__(256) void k_keys(uint32_t* __restrict__ keys) {
  int j = blockIdx.x * blockDim.x + threadIdx.x;
  if (j >= NSTEP) return;
#if PARTITIONABLE
  uint32_t o0, o1;
  threefry2x32(0u, 1u, 0u, (uint32_t)j, o0, o1);
  keys[2 * j] = o0; keys[2 * j + 1] = o1;
#else
  uint32_t w[2];
  #pragma unroll
  for (int q = 0; q < 2; ++q) {
    uint32_t m = (uint32_t)(2 * j + q);
    uint32_t lane = (m < NSTEP) ? m : (m - NSTEP);
    uint32_t o0, o1;
    threefry2x32(0u, 1u, lane, lane + NSTEP, o0, o1);
    w[q] = (m < NSTEP) ? o0 : o1;
  }
  keys[2 * j] = w[0]; keys[2 * j + 1] = w[1];
#endif
}

// wqT[k][j] = Wq[j][k]  (f32 transpose, once)
__global__ __launch_bounds__(256) void k_t32(const float* __restrict__ src,
                                             float* __restrict__ dst) {
  int idx = blockIdx.x * blockDim.x + threadIdx.x;   // Hn*Hn
  int k = idx >> 8, j = idx & 255;
  dst[idx] = src[j * Hn + k];
}

__global__ __launch_bounds__(256) void k_init(double* __restrict__ hA, double* __restrict__ hB,
                                              double* __restrict__ c,
                                              int* __restrict__ mask, int* __restrict__ chosen,
                                              float* __restrict__ out) {
  int idx = blockIdx.x * blockDim.x + threadIdx.x;   // Bn*Sn threads
  if (idx < Bn * Hn) { hA[idx] = 0.0; hB[idx] = 0.0; c[idx] = 0.0; }
  if (idx < Bn * Sn) mask[idx] = ((idx & (Sn - 1)) == 0) ? 1 : 0;
  if (idx < Bn) {
    chosen[idx] = 0;
    out[Bn * NSTEP + idx * Sn] = 0.0f;  // indices[:,0] = START
  }
}

// ---------------------------------------------------------------- LSTM cell (tiled)
// grid 256 = 16 b-tiles(16 rows) x 16 u-tiles(16 units = 64 gate-rows).
// 256 threads = 4 waves. Wave w owns rows b0+4w..+3 (scalar-loaded h),
// lanes = 64 gate-rows jj = g*16+u.  Weight tile f32 in LDS (pad 257).
// Exact same per-gate f64 accumulation order as previous rounds.
__global__ __launch_bounds__(256) void k_cell(
    const float* __restrict__ inp,      // (B,S,2)
    const int* chosen,                  // (B) or null (encoder)
    int s,                              // encoder step (x index + hs write)
    const double* __restrict__ wihe,    // (2,4H) f64
    const double* __restrict__ bias,    // (4H) f64
    const float* __restrict__ Whh,      // (4H,H) f32 original
    const double* h_in,                 // (B,H) f64
    double* __restrict__ h_out,         // (B,H) f64
    double* __restrict__ c,             // (B,H) f64
    float* hs) {                        // (B,S,H) f32 history or null
  __shared__ float  w32[64 * 257];
  __shared__ double g64[16 * 64];

  const int tid = threadIdx.x;
  const int bt = blockIdx.x >> 4, ut = blockIdx.x & 15;
  const int b0 = bt * 16, u0 = ut * 16;
  const int wave = tid >> 6, lane = tid & 63;
  const int g = lane >> 4, u = lane & 15;

  // stage weight tile: LDS[jj][k] = Whh[g*256 + u0 + u][k]
  for (int idx = tid; idx < 64 * 256; idx += 256) {
    int jj = idx >> 8, k = idx & 255;
    int gs = jj >> 4, us = jj & 15;
    w32[jj * 257 + k] = Whh[(size_t)(gs * 256 + u0 + us) * 256 + k];
  }
  __syncthreads();

  // rows for this wave (force SGPR)
  int r0 = __builtin_amdgcn_readfirstlane(b0 + wave * 4);
  const double* hr0 = h_in + (size_t)r0 * Hn;
  const double* hr1 = h_in + (size_t)(r0 + 1) * Hn;
  const double* hr2 = h_in + (size_t)(r0 + 2) * Hn;
  const double* hr3 = h_in + (size_t)(r0 + 3) * Hn;

  // x per row (scalar)
  double x0[4], x1[4];
  #pragma unroll
  for (int i = 0; i < 4; ++i) {
    int row = r0 + i;
    int col = (chosen != nullptr) ? chosen[row] : s;
    x0[i] = (double)inp[((size_t)row * Sn + col) * 2 + 0];
    x1[i] = (double)inp[((size_t)row * Sn + col) * 2 + 1];
  }

  // init acc with bias + x terms (same expression shape as prior rounds)
  const int jg = g * 256 + u0 + u;
  const double bj  = bias[jg];
  const double w0j = wihe[jg];
  const double w1j = wihe[Gn + jg];
  double acc[4];
  #pragma unroll
  for (int i = 0; i < 4; ++i) acc[i] = bj + x0[i] * w0j + x1[i] * w1j;

  // k-loop: acc[i] += h[r_i][k] * W[jg][k], k ascending (order preserved)
  const float* wrow = w32 + lane * 257;
  #pragma unroll 4
  for (int k = 0; k < Hn; ++k) {
    double wv = (double)wrow[k];
    acc[0] += hr0[k] * wv;
    acc[1] += hr1[k] * wv;
    acc[2] += hr2[k] * wv;
    acc[3] += hr3[k] * wv;
  }

  // exchange gates
  #pragma unroll
  for (int i = 0; i < 4; ++i) g64[(wave * 4 + i) * 64 + lane] = acc[i];
  __syncthreads();

  // cell update: thread t = (r, u)
  {
    const int r = tid >> 4, uu = tid & 15;
    double gi = g64[r * 64 + uu];
    double gf = g64[r * 64 + 16 + uu];
    double gg = g64[r * 64 + 32 + uu];
    double go = g64[r * 64 + 48 + uu];
    size_t ix = (size_t)(b0 + r) * Hn + (u0 + uu);
    double cn = sigmoid64(gf) * c[ix] + sigmoid64(gi) * tanh(gg);
    double hn = sigmoid64(go) * tanh(cn);
    c[ix] = cn;
    h_out[ix] = hn;
    if (hs != nullptr)
      hs[((size_t)(b0 + r) * Sn + s) * Hn + (u0 + uu)] = (float)hn;
  }
}

// ---------------------------------------------------------------- ref_proj (in-place)
// buf holds h-history f32 [(b,s)][k]; overwritten with ref_proj [(b,s)][t].
// grid 8192 blocks x 256 thr; block owns 16 flat rows. Wave w: rows +4w..+3
// (scalar loads — all reads of a wave's rows precede its writes; rows are
// block-exclusive, so in-place is safe). Wref streamed in k-chunks via LDS.
__global__ __launch_bounds__(256) void k_refproj(float* buf,
                                                 const float* __restrict__ wref) {
  __shared__ float wc[256 * 65];   // [t][kk], chunk of 64 k, pad 65

  const int tid = threadIdx.x;
  const int row0 = blockIdx.x * 16;
  const int wave = tid >> 6, lane = tid & 63;
  int r0 = __builtin_amdgcn_readfirstlane(row0 + wave * 4);
  const float* h0 = buf + (size_t)r0 * Hn;
  const float* h1 = buf + (size_t)(r0 + 1) * Hn;
  const float* h2 = buf + (size_t)(r0 + 2) * Hn;
  const float* h3 = buf + (size_t)(r0 + 3) * Hn;

  double acc[4][4];   // [row][tt], t = lane + 64*tt
  #pragma unroll
  for (int i = 0; i < 4; ++i)
    #pragma unroll
    for (int tt = 0; tt < 4; ++tt) acc[i][tt] = 0.0;

  for (int kc = 0; kc < 4; ++kc) {
    const int k0 = kc * 64;
    __syncthreads();
    for (int idx = tid; idx < 256 * 64; idx += 256) {
      int tcol = idx >> 6, kk = idx & 63;
      wc[tcol * 65 + kk] = wref[(size_t)tcol * Hn + k0 + kk];
    }
    __syncthreads();
    for (int kk = 0; kk < 64; ++kk) {
      int k = k0 + kk;
      double hv0 = (double)h0[k], hv1 = (double)h1[k];
      double hv2 = (double)h2[k], hv3 = (double)h3[k];
      #pragma unroll
      for (int tt = 0; tt < 4; ++tt) {
        double wv = (double)wc[(lane + 64 * tt) * 65 + kk];
        acc[0][tt] += hv0 * wv;
        acc[1][tt] += hv1 * wv;
        acc[2][tt] += hv2 * wv;
        acc[3][tt] += hv3 * wv;
      }
    }
  }

  // all reads done for this wave's rows -> write back in place
  #pragma unroll
  for (int i = 0; i < 4; ++i)
    #pragma unroll
    for (int tt = 0; tt < 4; ++tt)
      buf[(size_t)(r0 + i) * Hn + (lane + 64 * tt)] = (float)acc[i][tt];
}

// ---------------------------------------------------------------- attention + sample
// 1024 thr / block, one block per batch row.
// Phase 0: q-projection (4-way split-k across wave groups; wqT f32 k-major,
//          h via scalar loads), deterministic fixed-order combine.
// Phase 1: logits (wave per 32 s-rows, float4 ref loads, f64 shfl reduce).
// Phase 2: mask + threefry gumbel.  Phase 3: argmax | logsumexp waves.
__global__ __launch_bounds__(1024) void k_attn_sample(
    const double* __restrict__ h,       // (B,H) f64 current
    const float* __restrict__ wqT,      // (H,H) f32, [k][j]
    const float* __restrict__ ref32,    // (B,S,H)
    const float* __restrict__ v,        // (H)
    int* __restrict__ mask,             // (B,S)
    const uint32_t* __restrict__ keys,  // (511,2)
    int* __restrict__ chosen,           // (B)
    float* __restrict__ out,            // [B*511 logprobs][B*512 indices]
    int t) {
  __shared__ double qpart[4][256];
  __shared__ __align__(16) float qf[256];
  __shared__ float4 sv4[64];
  __shared__ double sl[Sn];
  __shared__ double zz[Sn];
  __shared__ int    sch;
  __shared__ double slse;

  const int b   = blockIdx.x;
  const int tid = threadIdx.x;
  const int w   = tid >> 6;
  const int l   = tid & 63;

  if (tid < 64) sv4[tid] = ((const float4*)v)[tid];

  // ---- phase 0: q[j] = sum_k h[b][k] * Wq[j][k]
  {
    const double* hb = h + (size_t)b * Hn;
    const int part = __builtin_amdgcn_readfirstlane(tid >> 8);
    const int jq = tid & 255;
    double acc = 0.0;
    const int kbase = part * 64;
    #pragma unroll 4
    for (int i = 0; i < 64; ++i) {
      int k = kbase + i;
      acc += hb[k] * (double)wqT[(size_t)k * Hn + jq];
    }
    qpart[part][jq] = acc;
  }
  __syncthreads();
  if (tid < 256) {
    double q = (qpart[0][tid] + qpart[1][tid]) + (qpart[2][tid] + qpart[3][tid]);
    qf[tid] = (float)q;
  }
  __syncthreads();

  // ---- phase 1: logits
  {
    const float4 qv = ((const float4*)qf)[l];
    const float4 vv = sv4[l];
    const float4* rbase = (const float4*)(ref32 + ((size_t)b * Sn) * Hn);
    #pragma unroll 2
    for (int p = 0; p < 32; ++p) {
      const int sErow = w * 32 + p;
      float4 rr = rbase[(size_t)sErow * 64 + l];
      double acc = (double)vv.x * (double)tanhf(qv.x + rr.x)
                 + (double)vv.y * (double)tanhf(qv.y + rr.y)
                 + (double)vv.z * (double)tanhf(qv.z + rr.z)
                 + (double)vv.w * (double)tanhf(qv.w + rr.w);
      #pragma unroll
      for (int m = 32; m >= 1; m >>= 1) acc += __shfl_xor(acc, m);
      if (l == 0) sl[sErow] = acc;
    }
  }
  __syncthreads();

  // ---- phase 2: mask + gumbel
  const uint32_t k0 = keys[2 * t], k1 = keys[2 * t + 1];
  if (tid < Sn) {
    const int sE = tid;
    double lg = mask[(size_t)b * Sn + sE] ? (double)MASK_VAL : sl[sE];
    uint32_t n = (uint32_t)(b * Sn + sE);
    uint32_t wrd = random_word(k0, k1, n);
    float uf = __uint_as_float((wrd >> 9) | 0x3f800000u) - 1.0f;
    uf = fmaxf(uf, 1.17549435e-38f);
    double gn = -log(-log((double)uf));
    sl[sE] = lg;
    zz[sE] = lg + gn;
  }
  __syncthreads();

  // ---- phase 3a (wave 0): argmax, first-index tie-break
  if (w == 0) {
    double bz = zz[l]; int bi = l;
    #pragma unroll
    for (int k = 1; k < 8; ++k) {
      int s2 = l + k * 64;
      double z2 = zz[s2];
      if (z2 > bz || (z2 == bz && s2 < bi)) { bz = z2; bi = s2; }
    }
    #pragma unroll
    for (int m = 32; m >= 1; m >>= 1) {
      double oz = __shfl_xor(bz, m);
      int    oi = __shfl_xor(bi, m);
      if (oz > bz || (oz == bz && oi < bi)) { bz = oz; bi = oi; }
    }
    if (l == 0) sch = bi;
  }
  // ---- phase 3b (wave 1): max + logsumexp
  if (w == 1) {
    double bm = sl[l];
    #pragma unroll
    for (int k = 1; k < 8; ++k) bm = fmax(bm, sl[l + k * 64]);
    #pragma unroll
    for (int m = 32; m >= 1; m >>= 1) bm = fmax(bm, __shfl_xor(bm, m));
    double ps = 0.0;
    #pragma unroll
    for (int k = 0; k < 8; ++k) ps += exp(sl[l + k * 64] - bm);
    #pragma unroll
    for (int m = 32; m >= 1; m >>= 1) ps += __shfl_xor(ps, m);
    if (l == 0) slse = bm + log(ps);
  }
  __syncthreads();

  if (tid == 0) {
    int ch = sch;
    double lp = sl[ch] - slse;
    out[(size_t)b * NSTEP + t] = (float)lp;
    out[(size_t)Bn * NSTEP + (size_t)b * Sn + (t + 1)] = (float)ch;
    mask[(size_t)b * Sn + ch] = 1;
    chosen[b] = ch;
  }
}

// ---------------------------------------------------------------- launch
extern "C" void kernel_launch(void* const* d_in, const int* in_sizes, int n_in,
                              void* d_out, int out_size, void* d_ws, size_t ws_size,
                              hipStream_t stream) {
  const float* inp  = (const float*)d_in[0];
  const float* wemb = (const float*)d_in[1];
  const float* eWih = (const float*)d_in[2];
  const float* eWhh = (const float*)d_in[3];
  const float* ebih = (const float*)d_in[4];
  const float* ebhh = (const float*)d_in[5];
  const float* dWih = (const float*)d_in[6];
  const float* dWhh = (const float*)d_in[7];
  const float* dbih = (const float*)d_in[8];
  const float* dbhh = (const float*)d_in[9];
  const float* Wq   = (const float*)d_in[10];
  const float* Wref = (const float*)d_in[11];
  const float* v    = (const float*)d_in[12];
  float* out = (float*)d_out;

  char* ws = (char*)d_ws;
  size_t off = 0;
  auto alloc = [&](size_t bytes) -> void* {
    void* p = (void*)(ws + off);
    off += (bytes + 255) & ~(size_t)255;
    return p;
  };
  float*    ref32  = (float*)   alloc((size_t)Bn * Sn * Hn * sizeof(float));  // h-hist then ref_proj
  double*   hA     = (double*)  alloc((size_t)Bn * Hn * sizeof(double));
  double*   hB     = (double*)  alloc((size_t)Bn * Hn * sizeof(double));
  double*   cbuf   = (double*)  alloc((size_t)Bn * Hn * sizeof(double));
  float*    wqT    = (float*)   alloc((size_t)Hn * Hn * sizeof(float));
  double*   wihe_e = (double*)  alloc(2 * Gn * sizeof(double));
  double*   wihe_d = (double*)  alloc(2 * Gn * sizeof(double));
  double*   bias_e = (double*)  alloc(Gn * sizeof(double));
  double*   bias_d = (double*)  alloc(Gn * sizeof(double));
  int*      maskp  = (int*)     alloc((size_t)Bn * Sn * sizeof(int));
  int*      chosen = (int*)     alloc(Bn * sizeof(int));
  uint32_t* keys   = (uint32_t*)alloc(2 * NSTEP * sizeof(uint32_t));
  (void)ws_size; (void)in_sizes; (void)n_in; (void)out_size;

  k_wihe<<<Gn / 256, 256, 0, stream>>>(wemb, eWih, ebih, ebhh, wihe_e, bias_e);
  k_wihe<<<Gn / 256, 256, 0, stream>>>(wemb, dWih, dbih, dbhh, wihe_d, bias_d);
  k_keys<<<2, 256, 0, stream>>>(keys);
  k_t32<<<(Hn * Hn) / 256, 256, 0, stream>>>(Wq, wqT);
  k_init<<<(Bn * Sn) / 256, 256, 0, stream>>>(hA, hB, cbuf, maskp, chosen, out);

  double* hcur = hA;
  double* hnxt = hB;

  // encoder: cell steps write f32 h-history into ref32
  for (int s = 0; s < Sn; ++s) {
    k_cell<<<256, 256, 0, stream>>>(inp, nullptr, s, wihe_e, bias_e, eWhh,
                                    hcur, hnxt, cbuf, ref32);
    double* tmp = hcur; hcur = hnxt; hnxt = tmp;
  }

  // in-place ref_proj GEMM over the h-history
  k_refproj<<<(Bn * Sn) / 16, 256, 0, stream>>>(ref32, Wref);

  // decoder
  for (int t = 0; t < NSTEP; ++t) {
    k_cell<<<256, 256, 0, stream>>>(inp, chosen, 0, wihe_d, bias_d, dWhh,
                                    hcur, hnxt, cbuf, nullptr);
    double* tmp = hcur; hcur = hnxt; hnxt = tmp;
    k_attn_sample<<<Bn, 1024, 0, stream>>>(hcur, wqT, ref32, v, maskp, keys,
                                           chosen, out, t);
  }
}